// Round 2
// baseline (369.498 us; speedup 1.0000x reference)
//
#include <hip/hip_runtime.h>
#include <stdint.h>

// x(4096x2048) @ W(2048x2048) + bias + probs, tanh.
static constexpr int MM = 4096;  // rows of x / out
static constexpr int KK = 2048;  // inner dim
static constexpr int NN = 2048;  // cols of out

typedef float floatx4 __attribute__((ext_vector_type(4)));
typedef __bf16 bf16x8 __attribute__((ext_vector_type(8)));
typedef unsigned short u16x8 __attribute__((ext_vector_type(8)));

__device__ __forceinline__ unsigned short bf16_rne(float x) {
  union { float f; uint32_t u; } c; c.f = x;
  uint32_t u = c.u;
  u += 0x7fffu + ((u >> 16) & 1u);
  return (unsigned short)(u >> 16);
}
__device__ __forceinline__ float bf16_as_f32(unsigned short h) {
  union { float f; uint32_t u; } c; c.u = ((uint32_t)h) << 16;
  return c.f;
}

// Swizzled-packed layout for A'/B' (row-major, 2048 k per row):
// the four 16B chunks of each 32-k panel are permuted per row:
//   physcol = (kc_logical + (row>>1)) & 3
// so that GEMM fragment reads (16 consecutive rows per ds_read_b128 phase)
// hit all 8 LDS bank-groups -> conflict-free. [fix for 8.4M SQ_LDS_BANK_CONFLICT]

// ---- Pre-pass 1: split x (f32, MMxKK) -> swizzle-packed hi/lo bf16 --------
__global__ __launch_bounds__(256) void split_x_kernel(
    const float* __restrict__ in, unsigned short* __restrict__ hi,
    unsigned short* __restrict__ lo, int nchunks) {
  int idx = blockIdx.x * 256 + threadIdx.x;  // one 8-elem chunk per thread
  if (idx >= nchunks) return;
  int row = idx >> 8;        // KK/8 = 256 chunks per row
  int ck = idx & 255;        // logical chunk in row
  int p = ck >> 2;           // 32-k panel
  int c = ck & 3;            // logical chunk within panel
  const float4* s = (const float4*)(in + (size_t)row * KK + ck * 8);
  float4 v0 = s[0], v1 = s[1];
  float vv[8] = {v0.x, v0.y, v0.z, v0.w, v1.x, v1.y, v1.z, v1.w};
  u16x8 h, l;
#pragma unroll
  for (int e = 0; e < 8; e++) {
    unsigned short hh = bf16_rne(vv[e]);
    h[e] = hh;
    l[e] = bf16_rne(vv[e] - bf16_as_f32(hh));
  }
  size_t dst = (size_t)row * KK + p * 32 + ((c + (row >> 1)) & 3) * 8;
  *(u16x8*)(hi + dst) = h;
  *(u16x8*)(lo + dst) = l;
}

// ---- Pre-pass 2: W (KKxNN f32) -> Bt hi/lo swizzle-packed (NNxKK bf16) ----
__global__ __launch_bounds__(256) void wsplit_kernel(
    const float* __restrict__ W, unsigned short* __restrict__ bhi,
    unsigned short* __restrict__ blo) {
  __shared__ float tile[64][65];
  const int tid = threadIdx.x;
  const int n0 = blockIdx.x * 64;
  const int k0 = blockIdx.y * 64;
#pragma unroll
  for (int i = 0; i < 4; i++) {
    int t = tid + i * 256;       // 0..1023
    int kr = t >> 4;             // 0..63
    int nc = (t & 15) * 4;       // 0..60
    const float4 v = *(const float4*)(W + (size_t)(k0 + kr) * NN + n0 + nc);
    tile[nc + 0][kr] = v.x;
    tile[nc + 1][kr] = v.y;
    tile[nc + 2][kr] = v.z;
    tile[nc + 3][kr] = v.w;
  }
  __syncthreads();
  const int nl = tid >> 2;       // 0..63 local n
  const int q = tid & 3;         // quarter: 16 k each -> 2 chunks
  const int n = n0 + nl;
#pragma unroll
  for (int cc = 0; cc < 2; cc++) {
    int c_loc = q * 2 + cc;      // local chunk 0..7
    int p_loc = c_loc >> 2;      // local panel 0..1
    int kc = c_loc & 3;          // logical chunk in panel
    u16x8 h, l;
#pragma unroll
    for (int e = 0; e < 8; e++) {
      float v = tile[nl][c_loc * 8 + e];
      unsigned short hh = bf16_rne(v);
      h[e] = hh;
      l[e] = bf16_rne(v - bf16_as_f32(hh));
    }
    size_t dst = (size_t)n * KK + (k0 + p_loc * 32) + ((kc + (n >> 1)) & 3) * 8;
    *(u16x8*)(bhi + dst) = h;
    *(u16x8*)(blo + dst) = l;
  }
}

// ---- Pre-pass 3: probs collapse (gate is translation-inv on uniform state)
__global__ __launch_bounds__(256) void bias_probs_kernel(
    const float* __restrict__ E, const float* __restrict__ cb,
    float* __restrict__ bias2) {
  int i = blockIdx.x * 256 + threadIdx.x;
  if (i >= NN) return;
  float p = 1.0f / 2048.0f;
#pragma unroll
  for (int d = 0; d < 9; d++) {
    const float* a = E + (size_t)d * (2048 * 2048) + (size_t)i * 2048;
#pragma unroll
    for (int t = 0; t < 3; t++) {
      float c = cosf(a[t]);
      p *= c * c;
    }
  }
  bias2[i] = cb[i] + p;
}

// ---- Main GEMM: 3-term bf16 split, 128x64 tile (4 blocks/CU), fused tanh --
#define GLL(dst, src)                                                        \
  __builtin_amdgcn_global_load_lds(                                          \
      (const __attribute__((address_space(1))) void*)(src),                  \
      (__attribute__((address_space(3))) void*)(dst), 16, 0, 0)

__global__ __launch_bounds__(256, 4) void gemm_tanh_kernel(
    const unsigned short* __restrict__ Ahi, const unsigned short* __restrict__ Alo,
    const unsigned short* __restrict__ Bhi, const unsigned short* __restrict__ Blo,
    const float* __restrict__ bias2, float* __restrict__ out) {
  __shared__ __align__(16) unsigned short sA[2][128 * 32];  // 16 KB
  __shared__ __align__(16) unsigned short sB[2][64 * 32];   //  8 KB

  const int tid = threadIdx.x;
  const int lane = tid & 63;
  const int wave = tid >> 6;
  const int wm = (wave >> 1) * 64;   // wave covers 64m x 32n
  const int wn = (wave & 1) * 32;
  const int bm = blockIdx.y * 128;
  const int bn = blockIdx.x * 64;

  const size_t a_base = (size_t)(bm + (tid >> 2)) * KK + (tid & 3) * 8;
  const size_t b_base = (size_t)(bn + (tid >> 2)) * KK + (tid & 3) * 8;
  const int lds_off = tid * 8;  // lane*16B contiguous per wave (GLL constraint)

  const int fm = lane & 15;
  const int kq = lane >> 4;          // logical k-chunk 0..3

  floatx4 acc[4][2];
#pragma unroll
  for (int i = 0; i < 4; i++)
#pragma unroll
    for (int j = 0; j < 2; j++) acc[i][j] = {0.f, 0.f, 0.f, 0.f};

  for (int k0 = 0; k0 < KK; k0 += 32) {
    GLL(&sA[0][lds_off],        Ahi + a_base + k0);
    GLL(&sA[0][lds_off + 2048], Ahi + a_base + k0 + (size_t)64 * KK);
    GLL(&sA[1][lds_off],        Alo + a_base + k0);
    GLL(&sA[1][lds_off + 2048], Alo + a_base + k0 + (size_t)64 * KK);
    GLL(&sB[0][lds_off],        Bhi + b_base + k0);
    GLL(&sB[1][lds_off],        Blo + b_base + k0);
    __syncthreads();

    bf16x8 fa[2][4], fb[2][2];
#pragma unroll
    for (int t = 0; t < 4; t++) {
      int rowA = wm + t * 16 + fm;
      int ao = rowA * 32 + ((kq + (rowA >> 1)) & 3) * 8;  // de-swizzle
      fa[0][t] = *(const bf16x8*)(&sA[0][ao]);
      fa[1][t] = *(const bf16x8*)(&sA[1][ao]);
    }
#pragma unroll
    for (int j = 0; j < 2; j++) {
      int rowB = wn + j * 16 + fm;
      int bo = rowB * 32 + ((kq + (rowB >> 1)) & 3) * 8;
      fb[0][j] = *(const bf16x8*)(&sB[0][bo]);
      fb[1][j] = *(const bf16x8*)(&sB[1][bo]);
    }
#pragma unroll
    for (int i = 0; i < 4; i++)
#pragma unroll
      for (int j = 0; j < 2; j++) {
        acc[i][j] = __builtin_amdgcn_mfma_f32_16x16x32_bf16(fa[0][i], fb[0][j], acc[i][j], 0, 0, 0);
        acc[i][j] = __builtin_amdgcn_mfma_f32_16x16x32_bf16(fa[0][i], fb[1][j], acc[i][j], 0, 0, 0);
        acc[i][j] = __builtin_amdgcn_mfma_f32_16x16x32_bf16(fa[1][i], fb[0][j], acc[i][j], 0, 0, 0);
      }
    __syncthreads();
  }

  // C/D layout: col=lane&15, row=(lane>>4)*4+reg  [m89/m91-verified]
  const int cr = (lane >> 4) * 4;
  const int cc = lane & 15;
#pragma unroll
  for (int j = 0; j < 2; j++) {
    int col = bn + wn + j * 16 + cc;
    float b2 = bias2[col];
#pragma unroll
    for (int i = 0; i < 4; i++) {
      int row0 = bm + wm + i * 16 + cr;
      floatx4 a = acc[i][j];
#pragma unroll
      for (int r = 0; r < 4; r++) {
        out[(size_t)(row0 + r) * NN + col] = tanhf(a[r] + b2);
      }
    }
  }
}

// ---- Fallback (ws too small): naive fp32 ---------------------------------
__global__ __launch_bounds__(256) void fallback_gemm(
    const float* __restrict__ x, const float* __restrict__ E,
    const float* __restrict__ W, const float* __restrict__ cb,
    float* __restrict__ out) {
  __shared__ float sA[16][16];
  __shared__ float sB[16][17];
  __shared__ float sbias[16];
  const int tx = threadIdx.x, ty = threadIdx.y;
  const int row = blockIdx.y * 16 + ty;
  const int col = blockIdx.x * 16 + tx;
  if (ty == 0) {
    float p = 1.0f / 2048.0f;
    for (int d = 0; d < 9; d++) {
      const float* a = E + (size_t)d * (2048 * 2048) + (size_t)col * 2048;
      for (int t = 0; t < 3; t++) { float c = cosf(a[t]); p *= c * c; }
    }
    sbias[tx] = p + cb[col];
  }
  float acc = 0.f;
  for (int k0 = 0; k0 < KK; k0 += 16) {
    __syncthreads();
    sA[ty][tx] = x[(size_t)row * KK + k0 + tx];
    sB[ty][tx] = W[(size_t)(k0 + ty) * NN + col];
    __syncthreads();
#pragma unroll
    for (int kk = 0; kk < 16; kk++) acc += sA[ty][kk] * sB[kk][tx];
  }
  out[(size_t)row * NN + col] = tanhf(acc + sbias[tx]);
}

extern "C" void kernel_launch(void* const* d_in, const int* in_sizes, int n_in,
                              void* d_out, int out_size, void* d_ws, size_t ws_size,
                              hipStream_t stream) {
  const float* x  = (const float*)d_in[0];
  const float* E  = (const float*)d_in[1];  // eternal_weights (9,2048,2048)
  const float* W  = (const float*)d_in[3];  // classical_weights (2048,2048)
  const float* cb = (const float*)d_in[4];  // classical_biases (2048,)
  float* out = (float*)d_out;

  const size_t MB = 1024 * 1024;
  const size_t need = 48 * MB + NN * sizeof(float);
  if (ws_size < need) {
    fallback_gemm<<<dim3(NN / 16, MM / 16), dim3(16, 16), 0, stream>>>(x, E, W, cb, out);
    return;
  }

  char* ws = (char*)d_ws;
  unsigned short* Ahi = (unsigned short*)(ws);            // 16 MB
  unsigned short* Alo = (unsigned short*)(ws + 16 * MB);  // 16 MB
  unsigned short* Bhi = (unsigned short*)(ws + 32 * MB);  //  8 MB
  unsigned short* Blo = (unsigned short*)(ws + 40 * MB);  //  8 MB
  float* bias2 = (float*)(ws + 48 * MB);                  //  8 KB

  const int nchunks = MM * KK / 8;  // 1,048,576
  split_x_kernel<<<dim3(nchunks / 256), dim3(256), 0, stream>>>(x, Ahi, Alo, nchunks);
  wsplit_kernel<<<dim3(NN / 64, KK / 64), dim3(256), 0, stream>>>(W, Bhi, Blo);
  bias_probs_kernel<<<dim3((NN + 255) / 256), dim3(256), 0, stream>>>(E, cb, bias2);
  gemm_tanh_kernel<<<dim3(NN / 64, MM / 128), dim3(256), 0, stream>>>(
      Ahi, Alo, Bhi, Blo, bias2, out);
}

// Round 3
// 316.013 us; speedup vs baseline: 1.1693x; 1.1693x over previous
//
#include <hip/hip_runtime.h>
#include <stdint.h>

// x(4096x2048) @ W(2048x2048) + bias + probs, tanh.
static constexpr int MM = 4096;  // rows of x / out
static constexpr int KK = 2048;  // inner dim
static constexpr int NN = 2048;  // cols of out

typedef float floatx4 __attribute__((ext_vector_type(4)));
typedef __bf16 bf16x8 __attribute__((ext_vector_type(8)));
typedef unsigned short u16x8 __attribute__((ext_vector_type(8)));

__device__ __forceinline__ unsigned short bf16_rne(float x) {
  union { float f; uint32_t u; } c; c.f = x;
  uint32_t u = c.u;
  u += 0x7fffu + ((u >> 16) & 1u);
  return (unsigned short)(u >> 16);
}
__device__ __forceinline__ float bf16_as_f32(unsigned short h) {
  union { float f; uint32_t u; } c; c.u = ((uint32_t)h) << 16;
  return c.f;
}
__device__ __forceinline__ float fast_tanh(float x) {
  // saturates correctly: exp->inf => 1, exp->0 => -1
  float e = __expf(2.0f * x);
  return 1.0f - 2.0f / (e + 1.0f);
}

// Swizzled-packed layout (row-major, 2048 k per row): within each 64-k group
// the eight 16B chunks are permuted per row: phys = (c8 + row) & 7.
// GEMM fragment reads (16 consecutive rows per ds_read_b128 phase, row stride
// 128B) then sweep all 32 banks at 2 lanes/bank -> conflict-free (m136).

// ---- Pre-pass 1: split x (f32, MMxKK) -> swizzle-packed hi/lo bf16 --------
__global__ __launch_bounds__(256) void split_x_kernel(
    const float* __restrict__ in, unsigned short* __restrict__ hi,
    unsigned short* __restrict__ lo, int nchunks) {
  int idx = blockIdx.x * 256 + threadIdx.x;  // one 8-elem chunk per thread
  if (idx >= nchunks) return;
  int row = idx >> 8;        // KK/8 = 256 chunks per row
  int ck = idx & 255;        // logical chunk in row
  int g = ck >> 3;           // 64-k group
  int c8 = ck & 7;           // logical chunk within group
  const float4* s = (const float4*)(in + (size_t)row * KK + ck * 8);
  float4 v0 = s[0], v1 = s[1];
  float vv[8] = {v0.x, v0.y, v0.z, v0.w, v1.x, v1.y, v1.z, v1.w};
  u16x8 h, l;
#pragma unroll
  for (int e = 0; e < 8; e++) {
    unsigned short hh = bf16_rne(vv[e]);
    h[e] = hh;
    l[e] = bf16_rne(vv[e] - bf16_as_f32(hh));
  }
  size_t dst = (size_t)row * KK + g * 64 + ((c8 + row) & 7) * 8;
  *(u16x8*)(hi + dst) = h;
  *(u16x8*)(lo + dst) = l;
}

// ---- Pre-pass 2: W (KKxNN f32) -> Bt hi/lo swizzle-packed (NNxKK bf16) ----
__global__ __launch_bounds__(256) void wsplit_kernel(
    const float* __restrict__ W, unsigned short* __restrict__ bhi,
    unsigned short* __restrict__ blo) {
  __shared__ float tile[64][65];
  const int tid = threadIdx.x;
  const int n0 = blockIdx.x * 64;
  const int k0 = blockIdx.y * 64;   // multiple of 64 -> one swizzle group
#pragma unroll
  for (int i = 0; i < 4; i++) {
    int t = tid + i * 256;       // 0..1023
    int kr = t >> 4;             // 0..63
    int nc = (t & 15) * 4;       // 0..60
    const float4 v = *(const float4*)(W + (size_t)(k0 + kr) * NN + n0 + nc);
    tile[nc + 0][kr] = v.x;
    tile[nc + 1][kr] = v.y;
    tile[nc + 2][kr] = v.z;
    tile[nc + 3][kr] = v.w;
  }
  __syncthreads();
  const int nl = tid >> 2;       // 0..63 local n
  const int q = tid & 3;         // 2 chunks each
  const int n = n0 + nl;
#pragma unroll
  for (int cc = 0; cc < 2; cc++) {
    int c8 = q * 2 + cc;         // logical chunk 0..7 within the 64-k group
    u16x8 h, l;
#pragma unroll
    for (int e = 0; e < 8; e++) {
      float v = tile[nl][c8 * 8 + e];
      unsigned short hh = bf16_rne(v);
      h[e] = hh;
      l[e] = bf16_rne(v - bf16_as_f32(hh));
    }
    size_t dst = (size_t)n * KK + k0 + ((c8 + n) & 7) * 8;
    *(u16x8*)(bhi + dst) = h;
    *(u16x8*)(blo + dst) = l;
  }
}

// ---- Pre-pass 3: probs collapse (gate is translation-inv on uniform state)
__global__ __launch_bounds__(64) void bias_probs_kernel(
    const float* __restrict__ E, const float* __restrict__ cb,
    float* __restrict__ bias2) {
  int i = blockIdx.x * 64 + threadIdx.x;
  if (i >= NN) return;
  float p = 1.0f / 2048.0f;
#pragma unroll
  for (int d = 0; d < 9; d++) {
    // rows are 16B-aligned: one float4 covers angles t=0..2
    const float4 a = *(const float4*)(E + (size_t)d * (2048 * 2048) + (size_t)i * 2048);
    float c0 = cosf(a.x), c1 = cosf(a.y), c2 = cosf(a.z);
    p *= (c0 * c0) * (c1 * c1) * (c2 * c2);
  }
  bias2[i] = cb[i] + p;
}

// ---- Main GEMM: 3-term bf16 split, 128x128 tile, BK=64, fused tanh --------
// grid 512 blocks = 2 blocks/CU grid-limited, so 64KB LDS costs nothing
// (m132's BK-large occupancy cliff does not apply here).
#define GLL(dst, src)                                                        \
  __builtin_amdgcn_global_load_lds(                                          \
      (const __attribute__((address_space(1))) void*)(src),                  \
      (__attribute__((address_space(3))) void*)(dst), 16, 0, 0)

__global__ __launch_bounds__(256, 2) void gemm_tanh_kernel(
    const unsigned short* __restrict__ Ahi, const unsigned short* __restrict__ Alo,
    const unsigned short* __restrict__ Bhi, const unsigned short* __restrict__ Blo,
    const float* __restrict__ bias2, float* __restrict__ out) {
  __shared__ __align__(16) unsigned short sA[2][128 * 64];  // 32 KB (hi/lo)
  __shared__ __align__(16) unsigned short sB[2][128 * 64];  // 32 KB (hi/lo)

  const int tid = threadIdx.x;
  const int lane = tid & 63;
  const int wave = tid >> 6;
  const int wm = (wave >> 1) * 64;
  const int wn = (wave & 1) * 64;
  const int bm = blockIdx.y * 128;
  const int bn = blockIdx.x * 128;

  // staging: pass p covers rows 32p..32p+31; thread t -> row t>>3, chunk t&7
  const int srow = tid >> 3;
  const size_t a_base = (size_t)(bm + srow) * KK + (tid & 7) * 8;
  const size_t b_base = (size_t)(bn + srow) * KK + (tid & 7) * 8;
  const int lds_off = tid * 8;  // lane*16B contiguous per wave (GLL constraint)

  const int fm = lane & 15;
  const int kq = lane >> 4;     // logical 16B chunk within 32-k subpanel

  floatx4 acc[4][4];
#pragma unroll
  for (int i = 0; i < 4; i++)
#pragma unroll
    for (int j = 0; j < 4; j++) acc[i][j] = {0.f, 0.f, 0.f, 0.f};

  for (int k0 = 0; k0 < KK; k0 += 64) {
#pragma unroll
    for (int p = 0; p < 4; p++) {
      const size_t go = k0 + (size_t)(32 * p) * KK;
      const int lo = p * 2048 + lds_off;
      GLL(&sA[0][lo], Ahi + a_base + go);
      GLL(&sA[1][lo], Alo + a_base + go);
      GLL(&sB[0][lo], Bhi + b_base + go);
      GLL(&sB[1][lo], Blo + b_base + go);
    }
    __syncthreads();

#pragma unroll
    for (int s = 0; s < 2; s++) {
      bf16x8 fa[2][4], fb[2][4];
#pragma unroll
      for (int t = 0; t < 4; t++) {
        int rowA = wm + t * 16 + fm;
        int ao = rowA * 64 + ((s * 4 + kq + rowA) & 7) * 8;  // de-swizzle
        fa[0][t] = *(const bf16x8*)(&sA[0][ao]);
        fa[1][t] = *(const bf16x8*)(&sA[1][ao]);
        int rowB = wn + t * 16 + fm;
        int bo = rowB * 64 + ((s * 4 + kq + rowB) & 7) * 8;
        fb[0][t] = *(const bf16x8*)(&sB[0][bo]);
        fb[1][t] = *(const bf16x8*)(&sB[1][bo]);
      }
#pragma unroll
      for (int i = 0; i < 4; i++)
#pragma unroll
        for (int j = 0; j < 4; j++) {
          acc[i][j] = __builtin_amdgcn_mfma_f32_16x16x32_bf16(fa[0][i], fb[0][j], acc[i][j], 0, 0, 0);
          acc[i][j] = __builtin_amdgcn_mfma_f32_16x16x32_bf16(fa[0][i], fb[1][j], acc[i][j], 0, 0, 0);
          acc[i][j] = __builtin_amdgcn_mfma_f32_16x16x32_bf16(fa[1][i], fb[0][j], acc[i][j], 0, 0, 0);
        }
    }
    __syncthreads();
  }

  // C/D layout: col=lane&15, row=(lane>>4)*4+reg  [m89/m91-verified]
  const int cr = (lane >> 4) * 4;
  const int cc = lane & 15;
#pragma unroll
  for (int j = 0; j < 4; j++) {
    int col = bn + wn + j * 16 + cc;
    float b2 = bias2[col];
#pragma unroll
    for (int i = 0; i < 4; i++) {
      int row0 = bm + wm + i * 16 + cr;
      floatx4 a = acc[i][j];
#pragma unroll
      for (int r = 0; r < 4; r++) {
        out[(size_t)(row0 + r) * NN + col] = fast_tanh(a[r] + b2);
      }
    }
  }
}

// ---- Fallback (ws too small): naive fp32 ---------------------------------
__global__ __launch_bounds__(256) void fallback_gemm(
    const float* __restrict__ x, const float* __restrict__ E,
    const float* __restrict__ W, const float* __restrict__ cb,
    float* __restrict__ out) {
  __shared__ float sA[16][16];
  __shared__ float sB[16][17];
  __shared__ float sbias[16];
  const int tx = threadIdx.x, ty = threadIdx.y;
  const int row = blockIdx.y * 16 + ty;
  const int col = blockIdx.x * 16 + tx;
  if (ty == 0) {
    float p = 1.0f / 2048.0f;
    for (int d = 0; d < 9; d++) {
      const float* a = E + (size_t)d * (2048 * 2048) + (size_t)col * 2048;
      for (int t = 0; t < 3; t++) { float c = cosf(a[t]); p *= c * c; }
    }
    sbias[tx] = p + cb[col];
  }
  float acc = 0.f;
  for (int k0 = 0; k0 < KK; k0 += 16) {
    __syncthreads();
    sA[ty][tx] = x[(size_t)row * KK + k0 + tx];
    sB[ty][tx] = W[(size_t)(k0 + ty) * NN + col];
    __syncthreads();
#pragma unroll
    for (int kk = 0; kk < 16; kk++) acc += sA[ty][kk] * sB[kk][tx];
  }
  out[(size_t)row * NN + col] = tanhf(acc + sbias[tx]);
}

extern "C" void kernel_launch(void* const* d_in, const int* in_sizes, int n_in,
                              void* d_out, int out_size, void* d_ws, size_t ws_size,
                              hipStream_t stream) {
  const float* x  = (const float*)d_in[0];
  const float* E  = (const float*)d_in[1];  // eternal_weights (9,2048,2048)
  const float* W  = (const float*)d_in[3];  // classical_weights (2048,2048)
  const float* cb = (const float*)d_in[4];  // classical_biases (2048,)
  float* out = (float*)d_out;

  const size_t MB = 1024 * 1024;
  const size_t need = 48 * MB + NN * sizeof(float);
  if (ws_size < need) {
    fallback_gemm<<<dim3(NN / 16, MM / 16), dim3(16, 16), 0, stream>>>(x, E, W, cb, out);
    return;
  }

  char* ws = (char*)d_ws;
  unsigned short* Ahi = (unsigned short*)(ws);            // 16 MB
  unsigned short* Alo = (unsigned short*)(ws + 16 * MB);  // 16 MB
  unsigned short* Bhi = (unsigned short*)(ws + 32 * MB);  //  8 MB
  unsigned short* Blo = (unsigned short*)(ws + 40 * MB);  //  8 MB
  float* bias2 = (float*)(ws + 48 * MB);                  //  8 KB

  const int nchunks = MM * KK / 8;  // 1,048,576
  split_x_kernel<<<dim3(nchunks / 256), dim3(256), 0, stream>>>(x, Ahi, Alo, nchunks);
  wsplit_kernel<<<dim3(NN / 64, KK / 64), dim3(256), 0, stream>>>(W, Bhi, Blo);
  bias_probs_kernel<<<dim3(NN / 64), dim3(64), 0, stream>>>(E, cb, bias2);
  gemm_tanh_kernel<<<dim3(NN / 128, MM / 128), dim3(256), 0, stream>>>(
      Ahi, Alo, Bhi, Blo, bias2, out);
}